// Round 13
// baseline (67.976 us; speedup 1.0000x reference)
//
#include <hip/hip_runtime.h>
#include <math.h>

#define NF 8
#define HID 128
#define TILE 448   // 4 waves x 16 pts x 7 iters; grid ~1179 <= 1280 (one round @5/CU)
#define NIT 7

typedef _Float16 f16;
typedef _Float16 h2 __attribute__((ext_vector_type(2)));
typedef _Float16 f16x8 __attribute__((ext_vector_type(8)));
typedef float f32x4 __attribute__((ext_vector_type(4)));
typedef unsigned int u32;
typedef u32 u32x2 __attribute__((ext_vector_type(2)));
typedef u32 u32x4 __attribute__((ext_vector_type(4)));

__device__ __forceinline__ u32 pk(float a, float b) {
    return __builtin_bit_cast(u32, __builtin_amdgcn_cvt_pkrtz(a, b));
}
__device__ __forceinline__ float dot2a(u32 a, u32 b, float c) {
    return __builtin_amdgcn_fdot2(__builtin_bit_cast(h2, a),
                                  __builtin_bit_cast(h2, b), c, false);
}

// ws int layout:
//   [0..7] counts, [8..15] starts, [16..23] tile-prefix, [24] total tiles
//   [32 .. 32+NB*8) per-block counts;  [32+NB*8 ..) perm

__device__ __forceinline__ int assign_field(float px, float py, float pz,
                                            const float* __restrict__ cen) {
    int best = 0;
    float bd = 3.4e38f;
#pragma unroll
    for (int k = 0; k < NF; ++k) {
        float dx = px - cen[k * 3 + 0];
        float dy = py - cen[k * 3 + 1];
        float dz = pz - cen[k * 3 + 2];
        float d = fmaf(dx, dx, fmaf(dy, dy, dz * dz));
        if (d < bd) { bd = d; best = k; }
    }
    return best;
}

// 512 threads, 4 points per thread; per-block counts only (no global atomics).
__global__ void k_count(const float* __restrict__ pos, const float* __restrict__ cen,
                        int n, int* __restrict__ blockcnt) {
    __shared__ int lc[NF];
    int tid = threadIdx.x;
    if (tid < NF) lc[tid] = 0;
    __syncthreads();
    int i4 = blockIdx.x * blockDim.x + tid;
    int base = i4 * 4;
    if (base + 3 < n) {
        const float4* p4 = (const float4*)pos;
        float4 a = p4[i4 * 3 + 0];
        float4 b = p4[i4 * 3 + 1];
        float4 c = p4[i4 * 3 + 2];
        atomicAdd(&lc[assign_field(a.x, a.y, a.z, cen)], 1);
        atomicAdd(&lc[assign_field(a.w, b.x, b.y, cen)], 1);
        atomicAdd(&lc[assign_field(b.z, b.w, c.x, cen)], 1);
        atomicAdd(&lc[assign_field(c.y, c.z, c.w, cen)], 1);
    } else {
        for (int i = base; i < n; ++i)
            atomicAdd(&lc[assign_field(pos[3 * i], pos[3 * i + 1], pos[3 * i + 2], cen)], 1);
    }
    __syncthreads();
    if (tid < NF) blockcnt[blockIdx.x * NF + tid] = lc[tid];
}

// Fused scan+scatter (cheap, perm only).
__global__ void k_scatscan(const float* __restrict__ pos, const float* __restrict__ cen,
                           int n, int nb, int* __restrict__ ws) {
    const int tid = threadIdx.x;
    const int f = tid >> 6, lane = tid & 63;
    const int* c = ws + 32;
    int* perm = ws + 32 + nb * NF;
    __shared__ int totals[NF], pres[NF], starts[NF], cur[NF];

    int tot = 0, pre = 0;
    for (int b = lane; b < nb; b += 64) {
        int v = c[b * NF + f];
        tot += v;
        if (b < (int)blockIdx.x) pre += v;
    }
#pragma unroll
    for (int d = 1; d < 64; d <<= 1) {
        tot += __shfl_xor(tot, d, 64);
        pre += __shfl_xor(pre, d, 64);
    }
    if (lane == 0) { totals[f] = tot; pres[f] = pre; }
    __syncthreads();
    if (tid == 0) {
        int s = 0, tp = 0;
        for (int k = 0; k < NF; ++k) {
            starts[k] = s;
            if (blockIdx.x == 0) {
                ws[k] = totals[k];
                ws[8 + k] = s;
                ws[16 + k] = tp;
            }
            s += totals[k];
            tp += (totals[k] + TILE - 1) / TILE;
        }
        if (blockIdx.x == 0) ws[24] = tp;
    }
    __syncthreads();
    if (tid < NF) cur[tid] = starts[tid] + pres[tid];
    __syncthreads();

    int i4 = blockIdx.x * blockDim.x + tid;
    int base = i4 * 4;
    if (base + 3 < n) {
        const float4* p4 = (const float4*)pos;
        float4 a = p4[i4 * 3 + 0];
        float4 b = p4[i4 * 3 + 1];
        float4 cc = p4[i4 * 3 + 2];
        int f0 = assign_field(a.x, a.y, a.z, cen);
        int f1 = assign_field(a.w, b.x, b.y, cen);
        int f2 = assign_field(b.z, b.w, cc.x, cen);
        int f3 = assign_field(cc.y, cc.z, cc.w, cen);
        perm[atomicAdd(&cur[f0], 1)] = base;
        perm[atomicAdd(&cur[f1], 1)] = base + 1;
        perm[atomicAdd(&cur[f2], 1)] = base + 2;
        perm[atomicAdd(&cur[f3], 1)] = base + 3;
    } else {
        for (int i = base; i < n; ++i) {
            int ff = assign_field(pos[3 * i], pos[3 * i + 1], pos[3 * i + 2], cen);
            perm[atomicAdd(&cur[ff], 1)] = i;
        }
    }
}

// Gather k_main (R11 structure = best, fence-free) with HALF-SIZE sH:
// L1/L2 run as two 64-hid half-passes through a 72-stride sH (9 KB vs 17).
// R4 tried this with explicit lgkmcnt(0) fences (5/iter) and regressed;
// now the compiler emits counted waits instead. LDS 30.8 KB <= 32 KB ->
// 5 blocks/CU cap; TILE 448 -> grid ~1179 <= 1280, ONE resident round at
// ~4.6 blocks/CU = ~18.3 waves/CU (+27% vs R11's 14.4).
// Same-wave DS ordering keeps single-buffered sH halves correct (L2a reads
// precede L1b writes in program order).
__global__ __launch_bounds__(256, 3) void k_main(
    const float* __restrict__ positions, const float* __restrict__ directions,
    const float* __restrict__ app,
    const float* __restrict__ Wd1, const float* __restrict__ bd1,
    const float* __restrict__ Wd2, const float* __restrict__ bd2,
    const float* __restrict__ Wc1, const float* __restrict__ bc1,
    const float* __restrict__ Wc2, const float* __restrict__ bc2,
    const int* __restrict__ ws, int nb, float* __restrict__ out) {
    const int b = blockIdx.x;
    if (b >= ws[24]) return;
    int f = 0;
#pragma unroll
    for (int k = 1; k < NF; ++k) if (b >= ws[16 + k]) f = k;
    const int tile = b - ws[16 + f];
    const int cnt = ws[f];
    const int start = ws[8 + f];
    const int* perm = ws + 32 + nb * NF;
    const int tid = threadIdx.x;
    const int w = tid >> 6, lane = tid & 63;
    const int pt = lane & 15, quad = lane >> 4;

    __shared__ __align__(16) f16 sWc1t[HID * 72];   // [h][72] permuted    18 KB
    __shared__ __align__(16) u32 sWc2p[64 * 4];     // [hp][ch] h2 pairs    1 KB
    __shared__ __align__(16) int sIdx[4][16];       //                    256 B
    __shared__ __align__(16) u32x2 sDir[4][16];     // pk'd dir           512 B
    __shared__ __align__(16) f16 sGeo[4][16][16];   // geo[15]+0 per pt     2 KB
    __shared__ __align__(16) f16 sH[4][16 * 72];    // per-wave, half-hid   9 KB

    // ---- stage Wc1^T (permuted, f16) and Wc2 pairs ----
    if (tid < HID) {
        int h = tid;
        f16* row = &sWc1t[h * 72];
        const float* Wf = Wc1 + f * 50 * HID;
        row[0] = (f16)Wf[0 * HID + h];
        row[1] = (f16)Wf[1 * HID + h];
        row[2] = (f16)Wf[2 * HID + h];
        row[3] = (f16)bc1[f * HID + h];
        row[4] = 0; row[5] = 0; row[6] = 0; row[7] = 0;
        for (int a = 0; a < 32; ++a) row[8 + a] = (f16)Wf[(18 + a) * HID + h];
        for (int g = 0; g < 15; ++g) row[40 + g] = (f16)Wf[(3 + g) * HID + h];
        for (int z = 55; z < 72; ++z) row[z] = 0;
    }
    if (tid >= 128 && tid < 192) {
        int hp = tid - 128;
        const float* W2 = Wc2 + f * HID * 3;
        sWc2p[hp * 4 + 0] = pk(W2[(2 * hp) * 3 + 0], W2[(2 * hp + 1) * 3 + 0]);
        sWc2p[hp * 4 + 1] = pk(W2[(2 * hp) * 3 + 1], W2[(2 * hp + 1) * 3 + 1]);
        sWc2p[hp * 4 + 2] = pk(W2[(2 * hp) * 3 + 2], W2[(2 * hp + 1) * 3 + 2]);
        sWc2p[hp * 4 + 3] = 0;
    }
    if (lane < 16) sGeo[w][pt][15] = (f16)0.f;   // never written afterwards

    // ---- resident fragments (from global) ----
    u32 wd1a0[8], wd1a1[8];
    if (quad == 0) {
        const float* W1 = Wd1 + f * 3 * HID;
        const float* B1 = bd1 + f * HID;
#pragma unroll
        for (int mt = 0; mt < 8; ++mt) {
            int m = 16 * mt + pt;
            wd1a0[mt] = pk(W1[m], W1[HID + m]);
            wd1a1[mt] = pk(W1[2 * HID + m], B1[m]);
        }
    } else {
#pragma unroll
        for (int mt = 0; mt < 8; ++mt) { wd1a0[mt] = 0; wd1a1[mt] = 0; }
    }
    f16x8 wd2b[4];
    {
        const float* W2d = Wd2 + f * HID * 16;
#pragma unroll
        for (int s = 0; s < 4; ++s) {
            u32x4 v;
#pragma unroll
            for (int jp = 0; jp < 4; ++jp) {
                int k = quad * 8 + 32 * s + 2 * jp;
                v[jp] = pk(W2d[k * 16 + pt], W2d[(k + 1) * 16 + pt]);
            }
            wd2b[s] = __builtin_bit_cast(f16x8, v);
        }
    }
    const float bd2v = bd2[f * 16 + pt];
    const float c20 = bc2[f * 3 + 0], c21 = bc2[f * 3 + 1], c22 = bc2[f * 3 + 2];
    __syncthreads();

    const int tstart = tile * TILE;
    const int cidx = (quad == 0) ? 3 : (quad - 1);   // app chunk this lane consumes

    // ---- prefetch registers (one iter ahead) ----
    int g_idx;
    float4 g_c0, g_c1;            // own app chunk (8 floats)
    float g_p0, g_p1, g_p2;       // quad0: pos;  quad1: dir
    {
        int plc = tstart + w * 16 + pt;
        if (plc > cnt - 1) plc = cnt - 1;
        g_idx = perm[start + plc];
        const float4* ap = (const float4*)(app + g_idx * 32 + cidx * 8);
        g_c0 = ap[0]; g_c1 = ap[1];
        if (quad == 0) {
            g_p0 = positions[g_idx * 3 + 0];
            g_p1 = positions[g_idx * 3 + 1];
            g_p2 = positions[g_idx * 3 + 2];
        } else if (quad == 1) {
            g_p0 = directions[g_idx * 3 + 0];
            g_p1 = directions[g_idx * 3 + 1];
            g_p2 = directions[g_idx * 3 + 2];
        }
    }

#pragma unroll 1
    for (int it = 0; it < NIT; ++it) {
        const int pbase = tstart + it * 64 + w * 16;
        if (pbase >= cnt) break;

        const int cur_idx = g_idx;
        const float4 cur_c0 = g_c0, cur_c1 = g_c1;
        const float cp0 = g_p0, cp1 = g_p1, cp2 = g_p2;
        if (quad == 0) {
            sIdx[w][pt] = cur_idx;
        } else if (quad == 1) {
            u32x2 d2; d2.x = pk(cp0, cp1); d2.y = pk(cp2, 1.f);
            sDir[w][pt] = d2;
        }

        // ---- issue next iter's gather (overlaps with compute below) ----
        {
            const int nbase = tstart + (it + 1) * 64 + w * 16;
            if (it + 1 < NIT && nbase < cnt) {
                int plc = nbase + pt;
                if (plc > cnt - 1) plc = cnt - 1;
                g_idx = perm[start + plc];
                const float4* ap = (const float4*)(app + g_idx * 32 + cidx * 8);
                g_c0 = ap[0]; g_c1 = ap[1];
                if (quad == 0) {
                    g_p0 = positions[g_idx * 3 + 0];
                    g_p1 = positions[g_idx * 3 + 1];
                    g_p2 = positions[g_idx * 3 + 2];
                } else if (quad == 1) {
                    g_p0 = directions[g_idx * 3 + 0];
                    g_p1 = directions[g_idx * 3 + 1];
                    g_p2 = directions[g_idx * 3 + 2];
                }
            }
        }

        // ---- L1/L2 as two 64-hid half passes through half-size sH ----
        u32x4 xv;
        xv.x = (quad == 0) ? pk(cp0, cp1) : 0u;
        xv.y = (quad == 0) ? pk(cp2, 1.f) : 0u;
        xv.z = 0u; xv.w = 0u;
        const f16x8 xb = __builtin_bit_cast(f16x8, xv);
        f32x4 dacc = {bd2v, bd2v, bd2v, bd2v};
        // half a: hid 0..63
#pragma unroll
        for (int mt = 0; mt < 4; ++mt) {
            u32x4 av; av.x = wd1a0[mt]; av.y = wd1a1[mt]; av.z = 0u; av.w = 0u;
            f16x8 af = __builtin_bit_cast(f16x8, av);
            f32x4 acc = {0.f, 0.f, 0.f, 0.f};
            acc = __builtin_amdgcn_mfma_f32_16x16x32_f16(af, xb, acc, 0, 0, 0);
            u32x2 hw;
            hw.x = pk(fmaxf(acc[0], 0.f), fmaxf(acc[1], 0.f));
            hw.y = pk(fmaxf(acc[2], 0.f), fmaxf(acc[3], 0.f));
            *(u32x2*)&sH[w][pt * 72 + 16 * mt + quad * 4] = hw;
        }
#pragma unroll
        for (int s = 0; s < 2; ++s) {
            f16x8 ha = __builtin_bit_cast(f16x8,
                *(const u32x4*)&sH[w][pt * 72 + quad * 8 + 32 * s]);
            dacc = __builtin_amdgcn_mfma_f32_16x16x32_f16(ha, wd2b[s], dacc, 0, 0, 0);
        }
        // half b: hid 64..127 (overwrites sH; L2a reads precede in order)
#pragma unroll
        for (int mt = 4; mt < 8; ++mt) {
            u32x4 av; av.x = wd1a0[mt]; av.y = wd1a1[mt]; av.z = 0u; av.w = 0u;
            f16x8 af = __builtin_bit_cast(f16x8, av);
            f32x4 acc = {0.f, 0.f, 0.f, 0.f};
            acc = __builtin_amdgcn_mfma_f32_16x16x32_f16(af, xb, acc, 0, 0, 0);
            u32x2 hw;
            hw.x = pk(fmaxf(acc[0], 0.f), fmaxf(acc[1], 0.f));
            hw.y = pk(fmaxf(acc[2], 0.f), fmaxf(acc[3], 0.f));
            *(u32x2*)&sH[w][pt * 72 + 16 * (mt - 4) + quad * 4] = hw;
        }
#pragma unroll
        for (int s = 2; s < 4; ++s) {
            f16x8 ha = __builtin_bit_cast(f16x8,
                *(const u32x4*)&sH[w][pt * 72 + quad * 8 + 32 * (s - 2)]);
            dacc = __builtin_amdgcn_mfma_f32_16x16x32_f16(ha, wd2b[s], dacc, 0, 0, 0);
        }
        if (pt == 0) {
            int4 si = *(const int4*)&sIdx[w][quad * 4];
            out[si.x * 4] = __expf(dacc[0]);
            out[si.y * 4] = __expf(dacc[1]);
            out[si.z * 4] = __expf(dacc[2]);
            out[si.w * 4] = __expf(dacc[3]);
        } else {
#pragma unroll
            for (int r = 0; r < 4; ++r)
                sGeo[w][quad * 4 + r][pt - 1] = (f16)dacc[r];
        }

        // ---- L3 (c1) + L4 (c2): cb fragments built in registers ----
        u32x4 capp;
        capp.x = pk(cur_c0.x, cur_c0.y); capp.y = pk(cur_c0.z, cur_c0.w);
        capp.z = pk(cur_c1.x, cur_c1.y); capp.w = pk(cur_c1.z, cur_c1.w);
        f16x8 cb0, cb1;
        {
            u32x4 t0 = capp;
            if (quad == 0) {
                u32x2 d2 = sDir[w][pt];
                t0.x = d2.x; t0.y = d2.y; t0.z = 0u; t0.w = 0u;
            }
            cb0 = __builtin_bit_cast(f16x8, t0);
            u32x4 t1;
            if (quad == 0) t1 = capp;
            else if (quad == 3) { t1.x = 0u; t1.y = 0u; t1.z = 0u; t1.w = 0u; }
            else t1 = *(const u32x4*)&sGeo[w][pt][(quad - 1) * 8];
            cb1 = __builtin_bit_cast(f16x8, t1);
        }
        float r0 = 0.f, r1 = 0.f, r2 = 0.f;
#pragma unroll
        for (int mt = 0; mt < 8; ++mt) {
            f16x8 wa0 = __builtin_bit_cast(f16x8,
                *(const u32x4*)&sWc1t[(16 * mt + pt) * 72 + quad * 8]);
            f16x8 wa1 = __builtin_bit_cast(f16x8,
                *(const u32x4*)&sWc1t[(16 * mt + pt) * 72 + quad * 8 + 32]);
            f32x4 cacc = {0.f, 0.f, 0.f, 0.f};
            cacc = __builtin_amdgcn_mfma_f32_16x16x32_f16(wa0, cb0, cacc, 0, 0, 0);
            cacc = __builtin_amdgcn_mfma_f32_16x16x32_f16(wa1, cb1, cacc, 0, 0, 0);
            u32 h01 = pk(fmaxf(cacc[0], 0.f), fmaxf(cacc[1], 0.f));
            u32 h23 = pk(fmaxf(cacc[2], 0.f), fmaxf(cacc[3], 0.f));
            u32x4 w01 = *(const u32x4*)&sWc2p[(8 * mt + 2 * quad) * 4];
            u32x4 w23 = *(const u32x4*)&sWc2p[(8 * mt + 2 * quad + 1) * 4];
            r0 = dot2a(h01, w01.x, r0); r0 = dot2a(h23, w23.x, r0);
            r1 = dot2a(h01, w01.y, r1); r1 = dot2a(h23, w23.y, r1);
            r2 = dot2a(h01, w01.z, r2); r2 = dot2a(h23, w23.z, r2);
        }
        r0 += __shfl_xor(r0, 16, 64); r0 += __shfl_xor(r0, 32, 64);
        r1 += __shfl_xor(r1, 16, 64); r1 += __shfl_xor(r1, 32, 64);
        r2 += __shfl_xor(r2, 16, 64); r2 += __shfl_xor(r2, 32, 64);
        if (quad == 0) {  // this lane's pt -> cur_idx still in register
            float s0 = 1.f / (1.f + __expf(-(r0 + c20)));
            float s1 = 1.f / (1.f + __expf(-(r1 + c21)));
            float s2 = 1.f / (1.f + __expf(-(r2 + c22)));
            out[cur_idx * 4 + 1] = s0;
            *(float2*)&out[cur_idx * 4 + 2] = make_float2(s1, s2);
        }
    }
}

extern "C" void kernel_launch(void* const* d_in, const int* in_sizes, int n_in,
                              void* d_out, int out_size, void* d_ws, size_t ws_size,
                              hipStream_t stream) {
    const float* positions = (const float*)d_in[0];
    const float* directions = (const float*)d_in[1];
    const float* app = (const float*)d_in[2];
    const float* centroids = (const float*)d_in[3];
    const float* Wd1 = (const float*)d_in[4];
    const float* bd1 = (const float*)d_in[5];
    const float* Wd2 = (const float*)d_in[6];
    const float* bd2 = (const float*)d_in[7];
    const float* Wc1 = (const float*)d_in[8];
    const float* bc1 = (const float*)d_in[9];
    const float* Wc2 = (const float*)d_in[10];
    const float* bc2 = (const float*)d_in[11];
    float* out = (float*)d_out;
    int* wsi = (int*)d_ws;
    const int n = in_sizes[0] / 3;
    const int nb = (n + 2047) / 2048;   // 512 threads x 4 pts
    const int max_tiles = (n + TILE - 1) / TILE + NF;

    k_count<<<nb, 512, 0, stream>>>(positions, centroids, n, wsi + 32);
    k_scatscan<<<nb, 512, 0, stream>>>(positions, centroids, n, nb, wsi);
    k_main<<<max_tiles, 256, 0, stream>>>(positions, directions, app, Wd1, bd1, Wd2,
                                          bd2, Wc1, bc1, Wc2, bc2, wsi, nb, out);
}

// Round 14
// 58.494 us; speedup vs baseline: 1.1621x; 1.1621x over previous
//
#include <hip/hip_runtime.h>
#include <math.h>

#define NF 8
#define HID 128
#define TILE 576   // 4 waves x 16 pts x 9 iters; grid ~919 <= 1024 (one round)
#define NIT 9

typedef _Float16 f16;
typedef _Float16 h2 __attribute__((ext_vector_type(2)));
typedef _Float16 f16x8 __attribute__((ext_vector_type(8)));
typedef float f32x4 __attribute__((ext_vector_type(4)));
typedef unsigned int u32;
typedef u32 u32x2 __attribute__((ext_vector_type(2)));
typedef u32 u32x4 __attribute__((ext_vector_type(4)));

__device__ __forceinline__ u32 pk(float a, float b) {
    return __builtin_bit_cast(u32, __builtin_amdgcn_cvt_pkrtz(a, b));
}
__device__ __forceinline__ float dot2a(u32 a, u32 b, float c) {
    return __builtin_amdgcn_fdot2(__builtin_bit_cast(h2, a),
                                  __builtin_bit_cast(h2, b), c, false);
}

// ws int layout:
//   [0..7] counts, [8..15] starts, [16..23] tile-prefix, [24] total tiles
//   [32 .. 32+NB*8) per-block counts;  [32+NB*8 ..) perm

__device__ __forceinline__ int assign_field(float px, float py, float pz,
                                            const float* __restrict__ cen) {
    int best = 0;
    float bd = 3.4e38f;
#pragma unroll
    for (int k = 0; k < NF; ++k) {
        float dx = px - cen[k * 3 + 0];
        float dy = py - cen[k * 3 + 1];
        float dz = pz - cen[k * 3 + 2];
        float d = fmaf(dx, dx, fmaf(dy, dy, dz * dz));
        if (d < bd) { bd = d; best = k; }
    }
    return best;
}

// 512 threads, 4 points per thread; per-block counts only (no global atomics).
__global__ void k_count(const float* __restrict__ pos, const float* __restrict__ cen,
                        int n, int* __restrict__ blockcnt) {
    __shared__ int lc[NF];
    int tid = threadIdx.x;
    if (tid < NF) lc[tid] = 0;
    __syncthreads();
    int i4 = blockIdx.x * blockDim.x + tid;
    int base = i4 * 4;
    if (base + 3 < n) {
        const float4* p4 = (const float4*)pos;
        float4 a = p4[i4 * 3 + 0];
        float4 b = p4[i4 * 3 + 1];
        float4 c = p4[i4 * 3 + 2];
        atomicAdd(&lc[assign_field(a.x, a.y, a.z, cen)], 1);
        atomicAdd(&lc[assign_field(a.w, b.x, b.y, cen)], 1);
        atomicAdd(&lc[assign_field(b.z, b.w, c.x, cen)], 1);
        atomicAdd(&lc[assign_field(c.y, c.z, c.w, cen)], 1);
    } else {
        for (int i = base; i < n; ++i)
            atomicAdd(&lc[assign_field(pos[3 * i], pos[3 * i + 1], pos[3 * i + 2], cen)], 1);
    }
    __syncthreads();
    if (tid < NF) blockcnt[blockIdx.x * NF + tid] = lc[tid];
}

// Fused scan+scatter (cheap, perm only).
__global__ void k_scatscan(const float* __restrict__ pos, const float* __restrict__ cen,
                           int n, int nb, int* __restrict__ ws) {
    const int tid = threadIdx.x;
    const int f = tid >> 6, lane = tid & 63;
    const int* c = ws + 32;
    int* perm = ws + 32 + nb * NF;
    __shared__ int totals[NF], pres[NF], starts[NF], cur[NF];

    int tot = 0, pre = 0;
    for (int b = lane; b < nb; b += 64) {
        int v = c[b * NF + f];
        tot += v;
        if (b < (int)blockIdx.x) pre += v;
    }
#pragma unroll
    for (int d = 1; d < 64; d <<= 1) {
        tot += __shfl_xor(tot, d, 64);
        pre += __shfl_xor(pre, d, 64);
    }
    if (lane == 0) { totals[f] = tot; pres[f] = pre; }
    __syncthreads();
    if (tid == 0) {
        int s = 0, tp = 0;
        for (int k = 0; k < NF; ++k) {
            starts[k] = s;
            if (blockIdx.x == 0) {
                ws[k] = totals[k];
                ws[8 + k] = s;
                ws[16 + k] = tp;
            }
            s += totals[k];
            tp += (totals[k] + TILE - 1) / TILE;
        }
        if (blockIdx.x == 0) ws[24] = tp;
    }
    __syncthreads();
    if (tid < NF) cur[tid] = starts[tid] + pres[tid];
    __syncthreads();

    int i4 = blockIdx.x * blockDim.x + tid;
    int base = i4 * 4;
    if (base + 3 < n) {
        const float4* p4 = (const float4*)pos;
        float4 a = p4[i4 * 3 + 0];
        float4 b = p4[i4 * 3 + 1];
        float4 cc = p4[i4 * 3 + 2];
        int f0 = assign_field(a.x, a.y, a.z, cen);
        int f1 = assign_field(a.w, b.x, b.y, cen);
        int f2 = assign_field(b.z, b.w, cc.x, cen);
        int f3 = assign_field(cc.y, cc.z, cc.w, cen);
        perm[atomicAdd(&cur[f0], 1)] = base;
        perm[atomicAdd(&cur[f1], 1)] = base + 1;
        perm[atomicAdd(&cur[f2], 1)] = base + 2;
        perm[atomicAdd(&cur[f3], 1)] = base + 3;
    } else {
        for (int i = base; i < n; ++i) {
            int ff = assign_field(pos[3 * i], pos[3 * i + 1], pos[3 * i + 2], cen);
            perm[atomicAdd(&cur[ff], 1)] = i;
        }
    }
}

// Gather k_main (R11 structure = best measured, 60.5us) + s_setprio around
// the compute block (T5): waves here are independent (per-wave LDS buffers,
// no intra-loop barriers), so waves sit at DIFFERENT iteration phases --
// raising priority for the MFMA/dot2a block and dropping it for the
// gather/stage phase lets compute-phase waves win issue arbitration
// (the regime where setprio measured +4-7% on attention; null only on
// barrier-lockstep kernels).
// Fence-free: all loop LDS buffers are per-wave; same-wave DS ops are
// ordered; compiler emits counted lgkmcnt before ds_read uses.
// Gather: each lane reads its own L3 app chunk (cidx=quad==0?3:quad-1),
// quad0 reads pos, quad1 reads dir (staged via sDir). LDS 39.9 KB ->
// 4 blocks/CU; TILE 576 -> grid ~919 <= 1024, one resident round.
__global__ __launch_bounds__(256, 3) void k_main(
    const float* __restrict__ positions, const float* __restrict__ directions,
    const float* __restrict__ app,
    const float* __restrict__ Wd1, const float* __restrict__ bd1,
    const float* __restrict__ Wd2, const float* __restrict__ bd2,
    const float* __restrict__ Wc1, const float* __restrict__ bc1,
    const float* __restrict__ Wc2, const float* __restrict__ bc2,
    const int* __restrict__ ws, int nb, float* __restrict__ out) {
    const int b = blockIdx.x;
    if (b >= ws[24]) return;
    int f = 0;
#pragma unroll
    for (int k = 1; k < NF; ++k) if (b >= ws[16 + k]) f = k;
    const int tile = b - ws[16 + f];
    const int cnt = ws[f];
    const int start = ws[8 + f];
    const int* perm = ws + 32 + nb * NF;
    const int tid = threadIdx.x;
    const int w = tid >> 6, lane = tid & 63;
    const int pt = lane & 15, quad = lane >> 4;

    __shared__ __align__(16) f16 sWc1t[HID * 72];   // [h][72] permuted    18 KB
    __shared__ __align__(16) u32 sWc2p[64 * 4];     // [hp][ch] h2 pairs    1 KB
    __shared__ __align__(16) int sIdx[4][16];       //                    256 B
    __shared__ __align__(16) u32x2 sDir[4][16];     // pk'd dir           512 B
    __shared__ __align__(16) f16 sGeo[4][16][16];   // geo[15]+0 per pt     2 KB
    __shared__ __align__(16) f16 sH[4][16 * 136];   // per-wave            17 KB

    // ---- stage Wc1^T (permuted, f16) and Wc2 pairs ----
    if (tid < HID) {
        int h = tid;
        f16* row = &sWc1t[h * 72];
        const float* Wf = Wc1 + f * 50 * HID;
        row[0] = (f16)Wf[0 * HID + h];
        row[1] = (f16)Wf[1 * HID + h];
        row[2] = (f16)Wf[2 * HID + h];
        row[3] = (f16)bc1[f * HID + h];
        row[4] = 0; row[5] = 0; row[6] = 0; row[7] = 0;
        for (int a = 0; a < 32; ++a) row[8 + a] = (f16)Wf[(18 + a) * HID + h];
        for (int g = 0; g < 15; ++g) row[40 + g] = (f16)Wf[(3 + g) * HID + h];
        for (int z = 55; z < 72; ++z) row[z] = 0;
    }
    if (tid >= 128 && tid < 192) {
        int hp = tid - 128;
        const float* W2 = Wc2 + f * HID * 3;
        sWc2p[hp * 4 + 0] = pk(W2[(2 * hp) * 3 + 0], W2[(2 * hp + 1) * 3 + 0]);
        sWc2p[hp * 4 + 1] = pk(W2[(2 * hp) * 3 + 1], W2[(2 * hp + 1) * 3 + 1]);
        sWc2p[hp * 4 + 2] = pk(W2[(2 * hp) * 3 + 2], W2[(2 * hp + 1) * 3 + 2]);
        sWc2p[hp * 4 + 3] = 0;
    }
    if (lane < 16) sGeo[w][pt][15] = (f16)0.f;   // never written afterwards

    // ---- resident fragments (from global) ----
    u32 wd1a0[8], wd1a1[8];
    if (quad == 0) {
        const float* W1 = Wd1 + f * 3 * HID;
        const float* B1 = bd1 + f * HID;
#pragma unroll
        for (int mt = 0; mt < 8; ++mt) {
            int m = 16 * mt + pt;
            wd1a0[mt] = pk(W1[m], W1[HID + m]);
            wd1a1[mt] = pk(W1[2 * HID + m], B1[m]);
        }
    } else {
#pragma unroll
        for (int mt = 0; mt < 8; ++mt) { wd1a0[mt] = 0; wd1a1[mt] = 0; }
    }
    f16x8 wd2b[4];
    {
        const float* W2d = Wd2 + f * HID * 16;
#pragma unroll
        for (int s = 0; s < 4; ++s) {
            u32x4 v;
#pragma unroll
            for (int jp = 0; jp < 4; ++jp) {
                int k = quad * 8 + 32 * s + 2 * jp;
                v[jp] = pk(W2d[k * 16 + pt], W2d[(k + 1) * 16 + pt]);
            }
            wd2b[s] = __builtin_bit_cast(f16x8, v);
        }
    }
    const float bd2v = bd2[f * 16 + pt];
    const float c20 = bc2[f * 3 + 0], c21 = bc2[f * 3 + 1], c22 = bc2[f * 3 + 2];
    __syncthreads();

    const int tstart = tile * TILE;
    const int cidx = (quad == 0) ? 3 : (quad - 1);   // app chunk this lane consumes

    // ---- prefetch registers (one iter ahead) ----
    int g_idx;
    float4 g_c0, g_c1;            // own app chunk (8 floats)
    float g_p0, g_p1, g_p2;       // quad0: pos;  quad1: dir
    {
        int plc = tstart + w * 16 + pt;
        if (plc > cnt - 1) plc = cnt - 1;
        g_idx = perm[start + plc];
        const float4* ap = (const float4*)(app + g_idx * 32 + cidx * 8);
        g_c0 = ap[0]; g_c1 = ap[1];
        if (quad == 0) {
            g_p0 = positions[g_idx * 3 + 0];
            g_p1 = positions[g_idx * 3 + 1];
            g_p2 = positions[g_idx * 3 + 2];
        } else if (quad == 1) {
            g_p0 = directions[g_idx * 3 + 0];
            g_p1 = directions[g_idx * 3 + 1];
            g_p2 = directions[g_idx * 3 + 2];
        }
    }

#pragma unroll 1
    for (int it = 0; it < NIT; ++it) {
        const int pbase = tstart + it * 64 + w * 16;
        if (pbase >= cnt) break;

        const int cur_idx = g_idx;
        const float4 cur_c0 = g_c0, cur_c1 = g_c1;
        const float cp0 = g_p0, cp1 = g_p1, cp2 = g_p2;
        if (quad == 0) {
            sIdx[w][pt] = cur_idx;
        } else if (quad == 1) {
            u32x2 d2; d2.x = pk(cp0, cp1); d2.y = pk(cp2, 1.f);
            sDir[w][pt] = d2;
        }

        // ---- issue next iter's gather (low prio; overlaps compute) ----
        {
            const int nbase = tstart + (it + 1) * 64 + w * 16;
            if (it + 1 < NIT && nbase < cnt) {
                int plc = nbase + pt;
                if (plc > cnt - 1) plc = cnt - 1;
                g_idx = perm[start + plc];
                const float4* ap = (const float4*)(app + g_idx * 32 + cidx * 8);
                g_c0 = ap[0]; g_c1 = ap[1];
                if (quad == 0) {
                    g_p0 = positions[g_idx * 3 + 0];
                    g_p1 = positions[g_idx * 3 + 1];
                    g_p2 = positions[g_idx * 3 + 2];
                } else if (quad == 1) {
                    g_p0 = directions[g_idx * 3 + 0];
                    g_p1 = directions[g_idx * 3 + 1];
                    g_p2 = directions[g_idx * 3 + 2];
                }
            }
        }

        __builtin_amdgcn_s_setprio(1);   // compute block: win arbitration

        // ---- L1 transposed: h^T[128x16] = Wd1^T (A resident) x X^T ----
        u32x4 xv;
        xv.x = (quad == 0) ? pk(cp0, cp1) : 0u;
        xv.y = (quad == 0) ? pk(cp2, 1.f) : 0u;
        xv.z = 0u; xv.w = 0u;
        const f16x8 xb = __builtin_bit_cast(f16x8, xv);
#pragma unroll
        for (int mt = 0; mt < 8; ++mt) {
            u32x4 av; av.x = wd1a0[mt]; av.y = wd1a1[mt]; av.z = 0u; av.w = 0u;
            f16x8 af = __builtin_bit_cast(f16x8, av);
            f32x4 acc = {0.f, 0.f, 0.f, 0.f};
            acc = __builtin_amdgcn_mfma_f32_16x16x32_f16(af, xb, acc, 0, 0, 0);
            u32x2 hw;
            hw.x = pk(fmaxf(acc[0], 0.f), fmaxf(acc[1], 0.f));
            hw.y = pk(fmaxf(acc[2], 0.f), fmaxf(acc[3], 0.f));
            *(u32x2*)&sH[w][pt * 136 + 16 * mt + quad * 4] = hw;
        }

        // ---- L2: dout[16x16] = h x Wd2, bias in C ----
        f32x4 dacc = {bd2v, bd2v, bd2v, bd2v};
#pragma unroll
        for (int s = 0; s < 4; ++s) {
            f16x8 ha = __builtin_bit_cast(f16x8,
                *(const u32x4*)&sH[w][pt * 136 + quad * 8 + 32 * s]);
            dacc = __builtin_amdgcn_mfma_f32_16x16x32_f16(ha, wd2b[s], dacc, 0, 0, 0);
        }
        if (pt == 0) {
            int4 si = *(const int4*)&sIdx[w][quad * 4];
            out[si.x * 4] = __expf(dacc[0]);
            out[si.y * 4] = __expf(dacc[1]);
            out[si.z * 4] = __expf(dacc[2]);
            out[si.w * 4] = __expf(dacc[3]);
        } else {
#pragma unroll
            for (int r = 0; r < 4; ++r)
                sGeo[w][quad * 4 + r][pt - 1] = (f16)dacc[r];
        }

        // ---- L3 (c1) + L4 (c2): cb fragments built in registers ----
        u32x4 capp;
        capp.x = pk(cur_c0.x, cur_c0.y); capp.y = pk(cur_c0.z, cur_c0.w);
        capp.z = pk(cur_c1.x, cur_c1.y); capp.w = pk(cur_c1.z, cur_c1.w);
        f16x8 cb0, cb1;
        {
            u32x4 t0 = capp;
            if (quad == 0) {
                u32x2 d2 = sDir[w][pt];
                t0.x = d2.x; t0.y = d2.y; t0.z = 0u; t0.w = 0u;
            }
            cb0 = __builtin_bit_cast(f16x8, t0);
            u32x4 t1;
            if (quad == 0) t1 = capp;
            else if (quad == 3) { t1.x = 0u; t1.y = 0u; t1.z = 0u; t1.w = 0u; }
            else t1 = *(const u32x4*)&sGeo[w][pt][(quad - 1) * 8];
            cb1 = __builtin_bit_cast(f16x8, t1);
        }
        float r0 = 0.f, r1 = 0.f, r2 = 0.f;
#pragma unroll
        for (int mt = 0; mt < 8; ++mt) {
            f16x8 wa0 = __builtin_bit_cast(f16x8,
                *(const u32x4*)&sWc1t[(16 * mt + pt) * 72 + quad * 8]);
            f16x8 wa1 = __builtin_bit_cast(f16x8,
                *(const u32x4*)&sWc1t[(16 * mt + pt) * 72 + quad * 8 + 32]);
            f32x4 cacc = {0.f, 0.f, 0.f, 0.f};
            cacc = __builtin_amdgcn_mfma_f32_16x16x32_f16(wa0, cb0, cacc, 0, 0, 0);
            cacc = __builtin_amdgcn_mfma_f32_16x16x32_f16(wa1, cb1, cacc, 0, 0, 0);
            u32 h01 = pk(fmaxf(cacc[0], 0.f), fmaxf(cacc[1], 0.f));
            u32 h23 = pk(fmaxf(cacc[2], 0.f), fmaxf(cacc[3], 0.f));
            u32x4 w01 = *(const u32x4*)&sWc2p[(8 * mt + 2 * quad) * 4];
            u32x4 w23 = *(const u32x4*)&sWc2p[(8 * mt + 2 * quad + 1) * 4];
            r0 = dot2a(h01, w01.x, r0); r0 = dot2a(h23, w23.x, r0);
            r1 = dot2a(h01, w01.y, r1); r1 = dot2a(h23, w23.y, r1);
            r2 = dot2a(h01, w01.z, r2); r2 = dot2a(h23, w23.z, r2);
        }
        __builtin_amdgcn_s_setprio(0);   // reduction/store phase: yield

        r0 += __shfl_xor(r0, 16, 64); r0 += __shfl_xor(r0, 32, 64);
        r1 += __shfl_xor(r1, 16, 64); r1 += __shfl_xor(r1, 32, 64);
        r2 += __shfl_xor(r2, 16, 64); r2 += __shfl_xor(r2, 32, 64);
        if (quad == 0) {  // this lane's pt -> cur_idx still in register
            float s0 = 1.f / (1.f + __expf(-(r0 + c20)));
            float s1 = 1.f / (1.f + __expf(-(r1 + c21)));
            float s2 = 1.f / (1.f + __expf(-(r2 + c22)));
            out[cur_idx * 4 + 1] = s0;
            *(float2*)&out[cur_idx * 4 + 2] = make_float2(s1, s2);
        }
    }
}

extern "C" void kernel_launch(void* const* d_in, const int* in_sizes, int n_in,
                              void* d_out, int out_size, void* d_ws, size_t ws_size,
                              hipStream_t stream) {
    const float* positions = (const float*)d_in[0];
    const float* directions = (const float*)d_in[1];
    const float* app = (const float*)d_in[2];
    const float* centroids = (const float*)d_in[3];
    const float* Wd1 = (const float*)d_in[4];
    const float* bd1 = (const float*)d_in[5];
    const float* Wd2 = (const float*)d_in[6];
    const float* bd2 = (const float*)d_in[7];
    const float* Wc1 = (const float*)d_in[8];
    const float* bc1 = (const float*)d_in[9];
    const float* Wc2 = (const float*)d_in[10];
    const float* bc2 = (const float*)d_in[11];
    float* out = (float*)d_out;
    int* wsi = (int*)d_ws;
    const int n = in_sizes[0] / 3;
    const int nb = (n + 2047) / 2048;   // 512 threads x 4 pts
    const int max_tiles = (n + TILE - 1) / TILE + NF;

    k_count<<<nb, 512, 0, stream>>>(positions, centroids, n, wsi + 32);
    k_scatscan<<<nb, 512, 0, stream>>>(positions, centroids, n, nb, wsi);
    k_main<<<max_tiles, 256, 0, stream>>>(positions, directions, app, Wd1, bd1, Wd2,
                                          bd2, Wc1, bc1, Wc2, bc2, wsi, nb, out);
}

// Round 15
// 57.480 us; speedup vs baseline: 1.1826x; 1.0176x over previous
//
#include <hip/hip_runtime.h>
#include <math.h>

#define NF 8
#define HID 128
#define TILE 576   // 4 waves x 16 pts x 9 iters; grid ~919 <= 1024 (one round)
#define NIT 9

typedef _Float16 f16;
typedef _Float16 h2 __attribute__((ext_vector_type(2)));
typedef _Float16 f16x8 __attribute__((ext_vector_type(8)));
typedef float f32x4 __attribute__((ext_vector_type(4)));
typedef unsigned int u32;
typedef u32 u32x2 __attribute__((ext_vector_type(2)));
typedef u32 u32x4 __attribute__((ext_vector_type(4)));

__device__ __forceinline__ u32 pk(float a, float b) {
    return __builtin_bit_cast(u32, __builtin_amdgcn_cvt_pkrtz(a, b));
}
__device__ __forceinline__ float dot2a(u32 a, u32 b, float c) {
    return __builtin_amdgcn_fdot2(__builtin_bit_cast(h2, a),
                                  __builtin_bit_cast(h2, b), c, false);
}

// ws int layout:
//   [0..7] counts, [8..15] starts, [16..23] tile-prefix, [24] total tiles
//   [32 .. 32+NB*8) per-block counts; [P0 ..) perm[n]; [P0+n ..) fid[n] bytes

__device__ __forceinline__ int assign_field(float px, float py, float pz,
                                            const float* __restrict__ cen) {
    int best = 0;
    float bd = 3.4e38f;
#pragma unroll
    for (int k = 0; k < NF; ++k) {
        float dx = px - cen[k * 3 + 0];
        float dy = py - cen[k * 3 + 1];
        float dz = pz - cen[k * 3 + 2];
        float d = fmaf(dx, dx, fmaf(dy, dy, dz * dz));
        if (d < bd) { bd = d; best = k; }
    }
    return best;
}

// 512 threads, 4 points per thread; per-block counts + packed field ids.
// fid written as one coalesced u32 per thread (4 bytes = 4 points).
__global__ void k_count(const float* __restrict__ pos, const float* __restrict__ cen,
                        int n, int* __restrict__ blockcnt, u32* __restrict__ fid) {
    __shared__ int lc[NF];
    int tid = threadIdx.x;
    if (tid < NF) lc[tid] = 0;
    __syncthreads();
    int i4 = blockIdx.x * blockDim.x + tid;
    int base = i4 * 4;
    if (base + 3 < n) {
        const float4* p4 = (const float4*)pos;
        float4 a = p4[i4 * 3 + 0];
        float4 b = p4[i4 * 3 + 1];
        float4 c = p4[i4 * 3 + 2];
        int f0 = assign_field(a.x, a.y, a.z, cen);
        int f1 = assign_field(a.w, b.x, b.y, cen);
        int f2 = assign_field(b.z, b.w, c.x, cen);
        int f3 = assign_field(c.y, c.z, c.w, cen);
        atomicAdd(&lc[f0], 1);
        atomicAdd(&lc[f1], 1);
        atomicAdd(&lc[f2], 1);
        atomicAdd(&lc[f3], 1);
        fid[i4] = (u32)f0 | ((u32)f1 << 8) | ((u32)f2 << 16) | ((u32)f3 << 24);
    } else if (base < n) {
        u32 packed = 0;
        for (int i = base; i < n; ++i) {
            int ff = assign_field(pos[3 * i], pos[3 * i + 1], pos[3 * i + 2], cen);
            atomicAdd(&lc[ff], 1);
            packed |= (u32)ff << (8 * (i - base));
        }
        fid[i4] = packed;
    }
    __syncthreads();
    if (tid < NF) blockcnt[blockIdx.x * NF + tid] = lc[tid];
}

// Fused scan+scatter: reads the 0.5MB fid array instead of re-reading 6.3MB
// of positions and re-running the 8-centroid distance computation.
__global__ void k_scatscan(int n, int nb, int* __restrict__ ws,
                           const u32* __restrict__ fid) {
    const int tid = threadIdx.x;
    const int f = tid >> 6, lane = tid & 63;
    const int* c = ws + 32;
    int* perm = ws + 32 + nb * NF;
    __shared__ int totals[NF], pres[NF], starts[NF], cur[NF];

    int tot = 0, pre = 0;
    for (int b = lane; b < nb; b += 64) {
        int v = c[b * NF + f];
        tot += v;
        if (b < (int)blockIdx.x) pre += v;
    }
#pragma unroll
    for (int d = 1; d < 64; d <<= 1) {
        tot += __shfl_xor(tot, d, 64);
        pre += __shfl_xor(pre, d, 64);
    }
    if (lane == 0) { totals[f] = tot; pres[f] = pre; }
    __syncthreads();
    if (tid == 0) {
        int s = 0, tp = 0;
        for (int k = 0; k < NF; ++k) {
            starts[k] = s;
            if (blockIdx.x == 0) {
                ws[k] = totals[k];
                ws[8 + k] = s;
                ws[16 + k] = tp;
            }
            s += totals[k];
            tp += (totals[k] + TILE - 1) / TILE;
        }
        if (blockIdx.x == 0) ws[24] = tp;
    }
    __syncthreads();
    if (tid < NF) cur[tid] = starts[tid] + pres[tid];
    __syncthreads();

    int i4 = blockIdx.x * blockDim.x + tid;
    int base = i4 * 4;
    if (base < n) {
        u32 packed = fid[i4];
        int lim = n - base; if (lim > 4) lim = 4;
        for (int j = 0; j < lim; ++j) {
            int ff = (packed >> (8 * j)) & 0xff;
            perm[atomicAdd(&cur[ff], 1)] = base + j;
        }
    }
}

// Gather k_main (R14 = best measured, 58.5us): fence-free, reg-cb,
// s_setprio(1) around the MFMA/dot2a compute block (T5: independent
// per-wave blocks at different phases -> arbitration hint pays, +3.3%).
// Gather: each lane reads its own L3 app chunk (cidx=quad==0?3:quad-1),
// quad0 reads pos, quad1 reads dir (staged via sDir). LDS 39.9 KB ->
// 4 blocks/CU; TILE 576 -> grid ~919 <= 1024, one resident round.
__global__ __launch_bounds__(256, 3) void k_main(
    const float* __restrict__ positions, const float* __restrict__ directions,
    const float* __restrict__ app,
    const float* __restrict__ Wd1, const float* __restrict__ bd1,
    const float* __restrict__ Wd2, const float* __restrict__ bd2,
    const float* __restrict__ Wc1, const float* __restrict__ bc1,
    const float* __restrict__ Wc2, const float* __restrict__ bc2,
    const int* __restrict__ ws, int nb, float* __restrict__ out) {
    const int b = blockIdx.x;
    if (b >= ws[24]) return;
    int f = 0;
#pragma unroll
    for (int k = 1; k < NF; ++k) if (b >= ws[16 + k]) f = k;
    const int tile = b - ws[16 + f];
    const int cnt = ws[f];
    const int start = ws[8 + f];
    const int* perm = ws + 32 + nb * NF;
    const int tid = threadIdx.x;
    const int w = tid >> 6, lane = tid & 63;
    const int pt = lane & 15, quad = lane >> 4;

    __shared__ __align__(16) f16 sWc1t[HID * 72];   // [h][72] permuted    18 KB
    __shared__ __align__(16) u32 sWc2p[64 * 4];     // [hp][ch] h2 pairs    1 KB
    __shared__ __align__(16) int sIdx[4][16];       //                    256 B
    __shared__ __align__(16) u32x2 sDir[4][16];     // pk'd dir           512 B
    __shared__ __align__(16) f16 sGeo[4][16][16];   // geo[15]+0 per pt     2 KB
    __shared__ __align__(16) f16 sH[4][16 * 136];   // per-wave            17 KB

    // ---- stage Wc1^T (permuted, f16) and Wc2 pairs ----
    if (tid < HID) {
        int h = tid;
        f16* row = &sWc1t[h * 72];
        const float* Wf = Wc1 + f * 50 * HID;
        row[0] = (f16)Wf[0 * HID + h];
        row[1] = (f16)Wf[1 * HID + h];
        row[2] = (f16)Wf[2 * HID + h];
        row[3] = (f16)bc1[f * HID + h];
        row[4] = 0; row[5] = 0; row[6] = 0; row[7] = 0;
        for (int a = 0; a < 32; ++a) row[8 + a] = (f16)Wf[(18 + a) * HID + h];
        for (int g = 0; g < 15; ++g) row[40 + g] = (f16)Wf[(3 + g) * HID + h];
        for (int z = 55; z < 72; ++z) row[z] = 0;
    }
    if (tid >= 128 && tid < 192) {
        int hp = tid - 128;
        const float* W2 = Wc2 + f * HID * 3;
        sWc2p[hp * 4 + 0] = pk(W2[(2 * hp) * 3 + 0], W2[(2 * hp + 1) * 3 + 0]);
        sWc2p[hp * 4 + 1] = pk(W2[(2 * hp) * 3 + 1], W2[(2 * hp + 1) * 3 + 1]);
        sWc2p[hp * 4 + 2] = pk(W2[(2 * hp) * 3 + 2], W2[(2 * hp + 1) * 3 + 2]);
        sWc2p[hp * 4 + 3] = 0;
    }
    if (lane < 16) sGeo[w][pt][15] = (f16)0.f;   // never written afterwards

    // ---- resident fragments (from global) ----
    u32 wd1a0[8], wd1a1[8];
    if (quad == 0) {
        const float* W1 = Wd1 + f * 3 * HID;
        const float* B1 = bd1 + f * HID;
#pragma unroll
        for (int mt = 0; mt < 8; ++mt) {
            int m = 16 * mt + pt;
            wd1a0[mt] = pk(W1[m], W1[HID + m]);
            wd1a1[mt] = pk(W1[2 * HID + m], B1[m]);
        }
    } else {
#pragma unroll
        for (int mt = 0; mt < 8; ++mt) { wd1a0[mt] = 0; wd1a1[mt] = 0; }
    }
    f16x8 wd2b[4];
    {
        const float* W2d = Wd2 + f * HID * 16;
#pragma unroll
        for (int s = 0; s < 4; ++s) {
            u32x4 v;
#pragma unroll
            for (int jp = 0; jp < 4; ++jp) {
                int k = quad * 8 + 32 * s + 2 * jp;
                v[jp] = pk(W2d[k * 16 + pt], W2d[(k + 1) * 16 + pt]);
            }
            wd2b[s] = __builtin_bit_cast(f16x8, v);
        }
    }
    const float bd2v = bd2[f * 16 + pt];
    const float c20 = bc2[f * 3 + 0], c21 = bc2[f * 3 + 1], c22 = bc2[f * 3 + 2];
    __syncthreads();

    const int tstart = tile * TILE;
    const int cidx = (quad == 0) ? 3 : (quad - 1);   // app chunk this lane consumes

    // ---- prefetch registers (one iter ahead) ----
    int g_idx;
    float4 g_c0, g_c1;            // own app chunk (8 floats)
    float g_p0, g_p1, g_p2;       // quad0: pos;  quad1: dir
    {
        int plc = tstart + w * 16 + pt;
        if (plc > cnt - 1) plc = cnt - 1;
        g_idx = perm[start + plc];
        const float4* ap = (const float4*)(app + g_idx * 32 + cidx * 8);
        g_c0 = ap[0]; g_c1 = ap[1];
        if (quad == 0) {
            g_p0 = positions[g_idx * 3 + 0];
            g_p1 = positions[g_idx * 3 + 1];
            g_p2 = positions[g_idx * 3 + 2];
        } else if (quad == 1) {
            g_p0 = directions[g_idx * 3 + 0];
            g_p1 = directions[g_idx * 3 + 1];
            g_p2 = directions[g_idx * 3 + 2];
        }
    }

#pragma unroll 1
    for (int it = 0; it < NIT; ++it) {
        const int pbase = tstart + it * 64 + w * 16;
        if (pbase >= cnt) break;

        const int cur_idx = g_idx;
        const float4 cur_c0 = g_c0, cur_c1 = g_c1;
        const float cp0 = g_p0, cp1 = g_p1, cp2 = g_p2;
        if (quad == 0) {
            sIdx[w][pt] = cur_idx;
        } else if (quad == 1) {
            u32x2 d2; d2.x = pk(cp0, cp1); d2.y = pk(cp2, 1.f);
            sDir[w][pt] = d2;
        }

        // ---- issue next iter's gather (low prio; overlaps compute) ----
        {
            const int nbase = tstart + (it + 1) * 64 + w * 16;
            if (it + 1 < NIT && nbase < cnt) {
                int plc = nbase + pt;
                if (plc > cnt - 1) plc = cnt - 1;
                g_idx = perm[start + plc];
                const float4* ap = (const float4*)(app + g_idx * 32 + cidx * 8);
                g_c0 = ap[0]; g_c1 = ap[1];
                if (quad == 0) {
                    g_p0 = positions[g_idx * 3 + 0];
                    g_p1 = positions[g_idx * 3 + 1];
                    g_p2 = positions[g_idx * 3 + 2];
                } else if (quad == 1) {
                    g_p0 = directions[g_idx * 3 + 0];
                    g_p1 = directions[g_idx * 3 + 1];
                    g_p2 = directions[g_idx * 3 + 2];
                }
            }
        }

        __builtin_amdgcn_s_setprio(1);   // compute block: win arbitration

        // ---- L1 transposed: h^T[128x16] = Wd1^T (A resident) x X^T ----
        u32x4 xv;
        xv.x = (quad == 0) ? pk(cp0, cp1) : 0u;
        xv.y = (quad == 0) ? pk(cp2, 1.f) : 0u;
        xv.z = 0u; xv.w = 0u;
        const f16x8 xb = __builtin_bit_cast(f16x8, xv);
#pragma unroll
        for (int mt = 0; mt < 8; ++mt) {
            u32x4 av; av.x = wd1a0[mt]; av.y = wd1a1[mt]; av.z = 0u; av.w = 0u;
            f16x8 af = __builtin_bit_cast(f16x8, av);
            f32x4 acc = {0.f, 0.f, 0.f, 0.f};
            acc = __builtin_amdgcn_mfma_f32_16x16x32_f16(af, xb, acc, 0, 0, 0);
            u32x2 hw;
            hw.x = pk(fmaxf(acc[0], 0.f), fmaxf(acc[1], 0.f));
            hw.y = pk(fmaxf(acc[2], 0.f), fmaxf(acc[3], 0.f));
            *(u32x2*)&sH[w][pt * 136 + 16 * mt + quad * 4] = hw;
        }

        // ---- L2: dout[16x16] = h x Wd2, bias in C ----
        f32x4 dacc = {bd2v, bd2v, bd2v, bd2v};
#pragma unroll
        for (int s = 0; s < 4; ++s) {
            f16x8 ha = __builtin_bit_cast(f16x8,
                *(const u32x4*)&sH[w][pt * 136 + quad * 8 + 32 * s]);
            dacc = __builtin_amdgcn_mfma_f32_16x16x32_f16(ha, wd2b[s], dacc, 0, 0, 0);
        }
        if (pt == 0) {
            int4 si = *(const int4*)&sIdx[w][quad * 4];
            out[si.x * 4] = __expf(dacc[0]);
            out[si.y * 4] = __expf(dacc[1]);
            out[si.z * 4] = __expf(dacc[2]);
            out[si.w * 4] = __expf(dacc[3]);
        } else {
#pragma unroll
            for (int r = 0; r < 4; ++r)
                sGeo[w][quad * 4 + r][pt - 1] = (f16)dacc[r];
        }

        // ---- L3 (c1) + L4 (c2): cb fragments built in registers ----
        u32x4 capp;
        capp.x = pk(cur_c0.x, cur_c0.y); capp.y = pk(cur_c0.z, cur_c0.w);
        capp.z = pk(cur_c1.x, cur_c1.y); capp.w = pk(cur_c1.z, cur_c1.w);
        f16x8 cb0, cb1;
        {
            u32x4 t0 = capp;
            if (quad == 0) {
                u32x2 d2 = sDir[w][pt];
                t0.x = d2.x; t0.y = d2.y; t0.z = 0u; t0.w = 0u;
            }
            cb0 = __builtin_bit_cast(f16x8, t0);
            u32x4 t1;
            if (quad == 0) t1 = capp;
            else if (quad == 3) { t1.x = 0u; t1.y = 0u; t1.z = 0u; t1.w = 0u; }
            else t1 = *(const u32x4*)&sGeo[w][pt][(quad - 1) * 8];
            cb1 = __builtin_bit_cast(f16x8, t1);
        }
        float r0 = 0.f, r1 = 0.f, r2 = 0.f;
#pragma unroll
        for (int mt = 0; mt < 8; ++mt) {
            f16x8 wa0 = __builtin_bit_cast(f16x8,
                *(const u32x4*)&sWc1t[(16 * mt + pt) * 72 + quad * 8]);
            f16x8 wa1 = __builtin_bit_cast(f16x8,
                *(const u32x4*)&sWc1t[(16 * mt + pt) * 72 + quad * 8 + 32]);
            f32x4 cacc = {0.f, 0.f, 0.f, 0.f};
            cacc = __builtin_amdgcn_mfma_f32_16x16x32_f16(wa0, cb0, cacc, 0, 0, 0);
            cacc = __builtin_amdgcn_mfma_f32_16x16x32_f16(wa1, cb1, cacc, 0, 0, 0);
            u32 h01 = pk(fmaxf(cacc[0], 0.f), fmaxf(cacc[1], 0.f));
            u32 h23 = pk(fmaxf(cacc[2], 0.f), fmaxf(cacc[3], 0.f));
            u32x4 w01 = *(const u32x4*)&sWc2p[(8 * mt + 2 * quad) * 4];
            u32x4 w23 = *(const u32x4*)&sWc2p[(8 * mt + 2 * quad + 1) * 4];
            r0 = dot2a(h01, w01.x, r0); r0 = dot2a(h23, w23.x, r0);
            r1 = dot2a(h01, w01.y, r1); r1 = dot2a(h23, w23.y, r1);
            r2 = dot2a(h01, w01.z, r2); r2 = dot2a(h23, w23.z, r2);
        }
        __builtin_amdgcn_s_setprio(0);   // reduction/store phase: yield

        r0 += __shfl_xor(r0, 16, 64); r0 += __shfl_xor(r0, 32, 64);
        r1 += __shfl_xor(r1, 16, 64); r1 += __shfl_xor(r1, 32, 64);
        r2 += __shfl_xor(r2, 16, 64); r2 += __shfl_xor(r2, 32, 64);
        if (quad == 0) {  // this lane's pt -> cur_idx still in register
            float s0 = 1.f / (1.f + __expf(-(r0 + c20)));
            float s1 = 1.f / (1.f + __expf(-(r1 + c21)));
            float s2 = 1.f / (1.f + __expf(-(r2 + c22)));
            out[cur_idx * 4 + 1] = s0;
            *(float2*)&out[cur_idx * 4 + 2] = make_float2(s1, s2);
        }
    }
}

extern "C" void kernel_launch(void* const* d_in, const int* in_sizes, int n_in,
                              void* d_out, int out_size, void* d_ws, size_t ws_size,
                              hipStream_t stream) {
    const float* positions = (const float*)d_in[0];
    const float* directions = (const float*)d_in[1];
    const float* app = (const float*)d_in[2];
    const float* centroids = (const float*)d_in[3];
    const float* Wd1 = (const float*)d_in[4];
    const float* bd1 = (const float*)d_in[5];
    const float* Wd2 = (const float*)d_in[6];
    const float* bd2 = (const float*)d_in[7];
    const float* Wc1 = (const float*)d_in[8];
    const float* bc1 = (const float*)d_in[9];
    const float* Wc2 = (const float*)d_in[10];
    const float* bc2 = (const float*)d_in[11];
    float* out = (float*)d_out;
    int* wsi = (int*)d_ws;
    const int n = in_sizes[0] / 3;
    const int nb = (n + 2047) / 2048;   // 512 threads x 4 pts
    const int max_tiles = (n + TILE - 1) / TILE + NF;

    // ws: header(32) | blockcnt(nb*8) | perm(n) | fid(n bytes, as u32[n/4])
    int* fid = wsi + 32 + nb * NF + n;

    k_count<<<nb, 512, 0, stream>>>(positions, centroids, n, wsi + 32, (u32*)fid);
    k_scatscan<<<nb, 512, 0, stream>>>(n, nb, wsi, (const u32*)fid);
    k_main<<<max_tiles, 256, 0, stream>>>(positions, directions, app, Wd1, bd1, Wd2,
                                          bd2, Wc1, bc1, Wc2, bc2, wsi, nb, out);
}